// Round 16
// baseline (441.128 us; speedup 1.0000x reference)
//
#include <hip/hip_runtime.h>

// Problem constants
#define N_NODES 4096
#define E_TOT   12288
#define F_NODE  64
#define F_EDGE  16
#define HDIM    128
#define NLAYER  4
#define NGRAPH  256

typedef _Float16 half8  __attribute__((ext_vector_type(8)));
typedef float    f32x4  __attribute__((ext_vector_type(4)));
typedef float    f32x16 __attribute__((ext_vector_type(16)));

// ---------------------------------------------------------------------------
// Repack e2_w (+e2_b as a 129th K-chunk) into f16 fragment-major layout for
// mfma_f32_32x32x16_f16 B operands:
//   page(k) = [8 kblk][4 cg][64 lane][8 j] f16 (16384 per page)
//   lane = ((h>>3)&1)*32 + (o&31) ; j = h&7 ; kblk = h>>4 ; cg = o>>5
// One block per (l,k) page: coalesced float4 reads -> LDS -> half8 writes.
// ---------------------------------------------------------------------------
__global__ __launch_bounds__(256)
void k_prep_w2(const float* __restrict__ e2w, const float* __restrict__ e2b,
               _Float16* __restrict__ W2F)
{
    __shared__ _Float16 pg[16384];
    int b = blockIdx.x;                 // 0 .. 4*129-1
    int l = b / 129, k = b - l * 129;
    const float* src = (k < 128) ? (e2w + ((size_t)(l * 128 + k)) * 16384)
                                 : (e2b + (size_t)l * 16384);
    int t = threadIdx.x;
#pragma unroll
    for (int it = 0; it < 16; ++it) {
        int p = it * 1024 + t * 4;      // linear f32 index (h*128+o)
        float4 v = *(const float4*)(src + p);
#pragma unroll
        for (int j4 = 0; j4 < 4; ++j4) {
            int p_ = p + j4;
            int h  = p_ >> 7, o = p_ & 127;
            int idx = ((h >> 4) * 4 + (o >> 5)) * 512
                    + ((h >> 3) & 1) * 256 + (o & 31) * 8 + (h & 7);
            float val = (j4 == 0) ? v.x : (j4 == 1) ? v.y : (j4 == 2) ? v.z : v.w;
            pg[idx] = (_Float16)val;
        }
    }
    __syncthreads();
    _Float16* dst = W2F + (size_t)b * 16384;
#pragma unroll
    for (int it = 0; it < 8; ++it) {
        int i = it * 2048 + t * 8;
        *(half8*)(dst + i) = *(const half8*)(pg + i);
    }
}

// h = x @ node_w + node_b  (also f16 copy for the gather path)
__global__ __launch_bounds__(128)
void k_node_enc(const float* __restrict__ x, const float* __restrict__ nw,
                const float* __restrict__ nb, float* __restrict__ h,
                _Float16* __restrict__ hf)
{
    __shared__ float xl[F_NODE];
    int n = blockIdx.x, o = threadIdx.x;
    if (o < F_NODE) xl[o] = x[(size_t)n * F_NODE + o];
    __syncthreads();
    float acc = nb[o];
#pragma unroll 8
    for (int f = 0; f < F_NODE; ++f) acc += xl[f] * nw[f * HDIM + o];
    h [(size_t)n * HDIM + o] = acc;
    hf[(size_t)n * HDIM + o] = (_Float16)acc;
}

__global__ void k_deg(const int* __restrict__ dst, int* __restrict__ deg)
{
    int e = blockIdx.x * 256 + threadIdx.x;
    if (e < E_TOT) atomicAdd(&deg[dst[e]], 1);
}

__global__ void k_invd(const int* __restrict__ deg, float* __restrict__ invd)
{
    int n = blockIdx.x * 256 + threadIdx.x;
    if (n < N_NODES) invd[n] = deg[n] > 0 ? 1.0f / (float)deg[n] : 0.0f;
}

// ef = relu(edge_attr @ e1_w[l] + e1_b[l]) stored f16 [E][136] (16B rows;
// col128 = 1.0 bias chunk, cols 129..135 unused).
#define EF_STRIDE 136
__global__ __launch_bounds__(256)
void k_edge_mlp(const float* __restrict__ ea, const float* __restrict__ w1,
                const float* __restrict__ b1, _Float16* __restrict__ efg)
{
    __shared__ float al[16][17];
    __shared__ float wl[16][HDIM];
    __shared__ float bl[HDIM];
    int t = threadIdx.x, e0 = blockIdx.x * 16;
    if (t < HDIM) bl[t] = b1[t];
    for (int i = t; i < F_EDGE * HDIM; i += 256) wl[i >> 7][i & 127] = w1[i];
    { int i = t; al[i >> 4][i & 15] = ea[(size_t)e0 * F_EDGE + i]; }
    __syncthreads();
    int e = t >> 4, og = t & 15;
    float acc[8];
#pragma unroll
    for (int j = 0; j < 8; ++j) acc[j] = bl[og * 8 + j];
#pragma unroll
    for (int f = 0; f < F_EDGE; ++f) {
        float a = al[e][f];
#pragma unroll
        for (int j = 0; j < 8; ++j) acc[j] += a * wl[f][og * 8 + j];
    }
    half8 o;
#pragma unroll
    for (int j = 0; j < 8; ++j) o[j] = (_Float16)fmaxf(acc[j], 0.f);
    *(half8*)&efg[(size_t)(e0 + e) * EF_STRIDE + og * 8] = o;
    if (og == 0) efg[(size_t)(e0 + e) * EF_STRIDE + 128] = (_Float16)1.0f;
}

// ---------------------------------------------------------------------------
// msg[e,o] = sum_k ef[e,k] * (h[src[e],:] @ W2[k,:,:]) ; atomic scatter-add.
// v17 = champion geometry (BM=64, 4 col-split waves, KSPLIT=4, 768 blocks,
// barrier-free register streaming) with the inner product switched from
// 16x16x32 to 32x32x16 MFMA: 16 MFMA instructions per wave-iter instead of
// 32, at IDENTICAL FLOPs / VALU work / atomic profile.  Discriminating
// experiment for the 15-round invariant "~50 cyc per MFMA instruction per
// SIMD regardless of waves/RF/schedule": if time follows instruction count,
// dur halves; if it follows pipe cycles, flat -> structural ceiling.
// A (32 rows x K=16): lane = row(l&31), k = (l>>5)*8+j.
// B (K=16 x 32 cols): lane = col(l&31) + 32*(k>>3), k j = low 3 bits.
// C/D (m74-verified): col = lane&31, row = (reg&3)+8*(reg>>2)+4*(lane>>5).
// ---------------------------------------------------------------------------
#define BM 64
#define KSPLIT 4
__global__ __launch_bounds__(256, 3)
void k_msg(const _Float16* __restrict__ W2L,   // layer base: [129][8][4][512] f16
           const _Float16* __restrict__ efg,   // [E][136] f16
           const _Float16* __restrict__ hf,    // [N][128] f16
           const int* __restrict__ srcIdx,
           const int* __restrict__ dstIdx,
           float* __restrict__ agg,            // [N][128] f32
           float* __restrict__ bns1,
           float* __restrict__ bns2)
{
    __shared__ _Float16 efs[BM][40];    // local k-slice of ef (<=33 cols + pad)

    const int tid  = threadIdx.x;
    const int lane = tid & 63;
    const int w    = tid >> 6;          // wave 0..3, owns cols [w*32, w*32+32)
    const int l31  = lane & 31;
    const int lh   = lane >> 5;         // 0/1: k-octet selector

    // XCD-grouped decode: bx%8 -> XCD; XCD pair {2ks,2ks+1} serves slice ks.
    const int bx    = blockIdx.x;
    const int ks    = (bx & 7) >> 1;
    const int tile  = (bx >> 3) * 2 + (bx & 1);           // 0..191
    const int e0    = tile * BM;
    const int kbase = (129 * ks) >> 2;                    // 0,32,64,96
    const int kcnt  = ((129 * (ks + 1)) >> 2) - kbase;    // 32,32,32,33

    // zero BN partial sums for the k_out that follows (stream-ordered)
    if (bx == 0 && tid < HDIM) { bns1[tid] = 0.f; bns2[tid] = 0.f; }

    // stage ef k-slice (64 rows x 5 half8)
    for (int i = tid; i < BM * 5; i += 256) {
        int r = i / 5, c = i - r * 5;
        *(half8*)&efs[r][c * 8] =
            *(const half8*)(efg + (size_t)(e0 + r) * EF_STRIDE + kbase + c * 8);
    }

    // h_src A-fragments: 2 row-tiles (32 edges each) x 8 kblk, 8 f16/lane.
    // lane: row = rt*32 + l31, h = kb*16 + lh*8 + j.
    half8 hs[2][8];
#pragma unroll
    for (int rt = 0; rt < 2; ++rt) {
        int s = srcIdx[e0 + rt * 32 + l31];
        const _Float16* hp = hf + (size_t)s * HDIM + lh * 8;
#pragma unroll
        for (int kb = 0; kb < 8; ++kb)
            hs[rt][kb] = *(const half8*)(hp + kb * 16);
    }

    __syncthreads();   // efs ready (only barrier in the kernel)

    // B fragment (kb) at bp + kk*16384 + kb*2048 (f16 units), lane*8 offset
    const _Float16* bp = W2L + (size_t)kbase * 16384 + w * 512 + lane * 8;

#define LDB(dst, kk, kb0) do {                                          \
        const _Float16* p_ = bp + (size_t)(kk) * 16384 + (kb0) * 2048;  \
        dst[0] = *(const half8*)(p_);                                   \
        dst[1] = *(const half8*)(p_ + 2048);                            \
        dst[2] = *(const half8*)(p_ + 4096);                            \
        dst[3] = *(const half8*)(p_ + 6144);                            \
    } while (0)

    half8 B0[4], B1[4];
    LDB(B0, 0, 0);      // k=0, kblk 0-3
    LDB(B1, 0, 4);      // k=0, kblk 4-7

    f32x16 acc[2];
#pragma unroll
    for (int rt = 0; rt < 2; ++rt)
#pragma unroll
        for (int d = 0; d < 16; ++d) acc[rt][d] = 0.f;

    for (int kk = 0; kk < kcnt; ++kk) {
        _Float16 efv[2];
#pragma unroll
        for (int rt = 0; rt < 2; ++rt) efv[rt] = efs[rt * 32 + l31][kk];

        // half 0: kblk 0-3 from B0
#pragma unroll
        for (int kb = 0; kb < 4; ++kb) {
#pragma unroll
            for (int rt = 0; rt < 2; ++rt) {
                half8 av = hs[rt][kb] * efv[rt];
                acc[rt] = __builtin_amdgcn_mfma_f32_32x32x16_f16(av, B0[kb], acc[rt], 0, 0, 0);
            }
        }
        if (kk + 1 < kcnt) LDB(B0, kk + 1, 0);   // refill right after last use

        // half 1: kblk 4-7 from B1
#pragma unroll
        for (int kb = 0; kb < 4; ++kb) {
#pragma unroll
            for (int rt = 0; rt < 2; ++rt) {
                half8 av = hs[rt][kb + 4] * efv[rt];
                acc[rt] = __builtin_amdgcn_mfma_f32_32x32x16_f16(av, B1[kb], acc[rt], 0, 0, 0);
            }
        }
        if (kk + 1 < kcnt) LDB(B1, kk + 1, 4);
    }
#undef LDB

    // epilogue: scatter-add partial msg into agg[dst]
    // C/D: col = lane&31, row = (reg&3) + 8*(reg>>2) + 4*(lane>>5)
#pragma unroll
    for (int rt = 0; rt < 2; ++rt) {
#pragma unroll
        for (int r = 0; r < 16; ++r) {
            int row = rt * 32 + (r & 3) + 8 * (r >> 2) + 4 * lh;
            int d   = dstIdx[e0 + row];
            int o   = w * 32 + l31;
            atomicAdd(&agg[(size_t)d * HDIM + o], acc[rt][r]);
        }
    }
}

// out = agg*inv_deg + h @ root_w[l] + conv_b[l]   (16 rows per block)
// 4x4 register tiles (128 thr); fused BN sum/sumsq via LDS reduce.
__global__ __launch_bounds__(128)
void k_out(const float* __restrict__ agg, const float* __restrict__ invd,
           const float* __restrict__ h, const float* __restrict__ rw,
           const float* __restrict__ cb, float* __restrict__ outb,
           float* __restrict__ bns1, float* __restrict__ bns2)
{
    __shared__ float hl[16][132];
    __shared__ float rb1[128], rb2[128];
    int t = threadIdx.x, n0 = blockIdx.x * 16;
    int rg = t >> 5, cg = t & 31;
    for (int i = t; i < 16 * HDIM; i += 128)
        hl[i >> 7][i & 127] = h[(size_t)(n0 + (i >> 7)) * HDIM + (i & 127)];
    rb1[t] = 0.f; rb2[t] = 0.f;
    __syncthreads();

    f32x4 cbv = *(const f32x4*)&cb[cg * 4];
    f32x4 acc[4];
#pragma unroll
    for (int i = 0; i < 4; ++i) {
        int r = n0 + rg * 4 + i;
        f32x4 a = *(const f32x4*)&agg[(size_t)r * HDIM + cg * 4];
        acc[i] = a * invd[r] + cbv;
    }
    for (int hh = 0; hh < HDIM; hh += 4) {
        f32x4 wv[4], hv[4];
#pragma unroll
        for (int j = 0; j < 4; ++j) wv[j] = *(const f32x4*)&rw[(hh + j) * HDIM + cg * 4];
#pragma unroll
        for (int i = 0; i < 4; ++i) hv[i] = *(const f32x4*)&hl[rg * 4 + i][hh];
#pragma unroll
        for (int i = 0; i < 4; ++i)
#pragma unroll
            for (int j = 0; j < 4; ++j)
                acc[i] += hv[i][j] * wv[j];
    }
    f32x4 s1v = {0.f,0.f,0.f,0.f}, s2v = {0.f,0.f,0.f,0.f};
#pragma unroll
    for (int i = 0; i < 4; ++i) {
        *(f32x4*)&outb[(size_t)(n0 + rg * 4 + i) * HDIM + cg * 4] = acc[i];
        s1v += acc[i];
        s2v += acc[i] * acc[i];
    }
#pragma unroll
    for (int j = 0; j < 4; ++j) {
        atomicAdd(&rb1[cg * 4 + j], s1v[j]);
        atomicAdd(&rb2[cg * 4 + j], s2v[j]);
    }
    __syncthreads();
    atomicAdd(&bns1[t], rb1[t]);
    atomicAdd(&bns2[t], rb2[t]);
}

// h += relu(bn(out)) with mu/rsig derived inline; refresh hf.
// Non-last layers: zero agg for the next layer's atomics.
// Last layer: fused global-mean-pool scatter.
__global__ void k_bn_apply(const float* __restrict__ outb, const float* __restrict__ bns1,
                           const float* __restrict__ bns2, const float* __restrict__ g,
                           const float* __restrict__ b, float* __restrict__ h,
                           _Float16* __restrict__ hf, float* __restrict__ agg,
                           const int* __restrict__ batch, float* __restrict__ pooled,
                           int* __restrict__ cnt, int last)
{
    int i = blockIdx.x * 256 + threadIdx.x;   // < N*128
    int o = i & (HDIM - 1);
    const float inv_n = 1.0f / (float)N_NODES;
    float m   = bns1[o] * inv_n;
    float var = bns2[o] * inv_n - m * m;
    float rs  = rsqrtf(var + 1e-5f);
    float v  = (outb[i] - m) * rs * g[o] + b[o];
    float hn = h[i] + fmaxf(v, 0.f);
    h[i]  = hn;
    hf[i] = (_Float16)hn;
    if (!last) {
        agg[i] = 0.f;
    } else {
        int n  = i >> 7;
        int gg = batch[n];
        atomicAdd(&pooled[(size_t)gg * HDIM + o], hn);
        if (o == 0) atomicAdd(&cnt[gg], 1);
    }
}

__global__ __launch_bounds__(128)
void k_head(const float* __restrict__ pooled, const int* __restrict__ cnt,
            const float* __restrict__ w1, const float* __restrict__ b1,
            const float* __restrict__ w2, const float* __restrict__ b2,
            float* __restrict__ y)
{
    __shared__ float pl[HDIM];
    __shared__ float red[HDIM];
    int g = blockIdx.x, o = threadIdx.x;
    float ic = 1.0f / (float)max(cnt[g], 1);
    pl[o] = pooled[(size_t)g * HDIM + o] * ic;
    __syncthreads();
    float t = b1[o];
#pragma unroll 8
    for (int hh = 0; hh < HDIM; ++hh) t += pl[hh] * w1[hh * HDIM + o];
    t = fmaxf(t, 0.f);
    red[o] = t * w2[o];
    __syncthreads();
    for (int s = 64; s > 0; s >>= 1) {
        if (o < s) red[o] += red[o + s];
        __syncthreads();
    }
    if (o == 0) y[g] = red[0] + b2[0];
}

// ---------------------------------------------------------------------------
extern "C" void kernel_launch(void* const* d_in, const int* in_sizes, int n_in,
                              void* d_out, int out_size, void* d_ws, size_t ws_size,
                              hipStream_t stream)
{
    const float* x      = (const float*)d_in[0];
    const int*   ei     = (const int*)  d_in[1];
    const float* ea     = (const float*)d_in[2];
    const int*   batch  = (const int*)  d_in[3];
    const float* node_w = (const float*)d_in[4];
    const float* node_b = (const float*)d_in[5];
    const float* e1w    = (const float*)d_in[6];
    const float* e1b    = (const float*)d_in[7];
    const float* e2w    = (const float*)d_in[8];
    const float* e2b    = (const float*)d_in[9];
    const float* rw     = (const float*)d_in[10];
    const float* cb     = (const float*)d_in[11];
    const float* bng    = (const float*)d_in[12];
    const float* bnb    = (const float*)d_in[13];
    const float* hw1    = (const float*)d_in[14];
    const float* hb1    = (const float*)d_in[15];
    const float* hw2    = (const float*)d_in[16];
    const float* hb2    = (const float*)d_in[17];
    float* y = (float*)d_out;

    // workspace carve-up (~27.8 MB, all 256B-aligned chunks)
    char* ws = (char*)d_ws;
    _Float16* W2F  = (_Float16*)ws; ws += 16908288;  // 4*129*16384 f16
    float*    h    = (float*)ws;    ws += 2097152;
    _Float16* hf   = (_Float16*)ws; ws += 1048576;
    _Float16* efg  = (_Float16*)ws; ws += 3342336;   // E*136 f16
    float*    agg  = (float*)ws;    ws += 2097152;   // [N][128] f32
    float*    bns1 = (float*)ws;    ws += 512;       // BN sum
    float*    bns2 = (float*)ws;    ws += 512;       // BN sumsq
    float*    outb = (float*)ws;    ws += 2097152;
    int*      deg  = (int*)ws;      ws += 16384;
    float*    invd = (float*)ws;    ws += 16384;
    float*    pooled = (float*)ws;  ws += 131072;
    int*      cnt  = (int*)ws;      ws += 1024;

    const int* src = ei;
    const int* dst = ei + E_TOT;

    k_prep_w2<<<NLAYER * 129, 256, 0, stream>>>(e2w, e2b, W2F);
    k_node_enc<<<N_NODES, 128, 0, stream>>>(x, node_w, node_b, h, hf);
    hipMemsetAsync(deg, 0, N_NODES * sizeof(int), stream);
    k_deg<<<(E_TOT + 255) / 256, 256, 0, stream>>>(dst, deg);
    k_invd<<<(N_NODES + 255) / 256, 256, 0, stream>>>(deg, invd);
    // agg zero for layer 0; pooled+cnt zero (contiguous => one memset)
    hipMemsetAsync(agg, 0, (size_t)N_NODES * HDIM * sizeof(float), stream);
    hipMemsetAsync(pooled, 0, (size_t)NGRAPH * HDIM * sizeof(float) + NGRAPH * sizeof(int), stream);

    for (int l = 0; l < NLAYER; ++l) {
        k_edge_mlp<<<E_TOT / 16, 256, 0, stream>>>(ea, e1w + l * F_EDGE * HDIM,
                                                   e1b + l * HDIM, efg);
        k_msg<<<(E_TOT / BM) * KSPLIT, 256, 0, stream>>>(
            W2F + (size_t)l * 129 * 16384, efg, hf, src, dst, agg, bns1, bns2);
        k_out<<<N_NODES / 16, 128, 0, stream>>>(agg, invd, h,
                                                rw + l * HDIM * HDIM,
                                                cb + l * HDIM, outb, bns1, bns2);
        k_bn_apply<<<(N_NODES * HDIM) / 256, 256, 0, stream>>>(
            outb, bns1, bns2, bng + l * HDIM, bnb + l * HDIM, h, hf,
            agg, batch, pooled, cnt, (l == NLAYER - 1) ? 1 : 0);
    }

    k_head<<<NGRAPH, 128, 0, stream>>>(pooled, cnt, hw1, hb1, hw2, hb2, y);
}

// Round 17
// 412.453 us; speedup vs baseline: 1.0695x; 1.0695x over previous
//
#include <hip/hip_runtime.h>

// Problem constants
#define N_NODES 4096
#define E_TOT   12288
#define F_NODE  64
#define F_EDGE  16
#define HDIM    128
#define NLAYER  4
#define NGRAPH  256

typedef _Float16 half8 __attribute__((ext_vector_type(8)));
typedef float    f32x4 __attribute__((ext_vector_type(4)));

// ---------------------------------------------------------------------------
// Repack e2_w (+e2_b as a 129th K-chunk) into f16 "fragment-major" layout:
// W2F[((l*129 + k)*32 + chunk)*512 + lane*8 + j]
//   chunk = hc*8 + ot ;  h = hc*32 + (lane>>4)*8 + j ;  o = ot*16 + (lane&15)
// One block per (l,k) page: coalesced float4 reads -> LDS transpose ->
// coalesced half8 writes.
// ---------------------------------------------------------------------------
__global__ __launch_bounds__(256)
void k_prep_w2(const float* __restrict__ e2w, const float* __restrict__ e2b,
               _Float16* __restrict__ W2F)
{
    __shared__ _Float16 pg[16384];
    int b = blockIdx.x;                 // 0 .. 4*129-1
    int l = b / 129, k = b - l * 129;
    const float* src = (k < 128) ? (e2w + ((size_t)(l * 128 + k)) * 16384)
                                 : (e2b + (size_t)l * 16384);
    int t = threadIdx.x;
#pragma unroll
    for (int it = 0; it < 16; ++it) {
        int p = it * 1024 + t * 4;      // linear f32 index (h*128+o)
        float4 v = *(const float4*)(src + p);
#pragma unroll
        for (int j4 = 0; j4 < 4; ++j4) {
            int p_ = p + j4;
            int h  = p_ >> 7, o = p_ & 127;
            int idx = ((h >> 5) * 8 + (o >> 4)) * 512
                    + (((h >> 3) & 3) * 16 + (o & 15)) * 8 + (h & 7);
            float val = (j4 == 0) ? v.x : (j4 == 1) ? v.y : (j4 == 2) ? v.z : v.w;
            pg[idx] = (_Float16)val;
        }
    }
    __syncthreads();
    _Float16* dst = W2F + (size_t)b * 16384;
#pragma unroll
    for (int it = 0; it < 8; ++it) {
        int i = it * 2048 + t * 8;
        *(half8*)(dst + i) = *(const half8*)(pg + i);
    }
}

// h = x @ node_w + node_b  (also f16 copy for the gather path)
__global__ __launch_bounds__(128)
void k_node_enc(const float* __restrict__ x, const float* __restrict__ nw,
                const float* __restrict__ nb, float* __restrict__ h,
                _Float16* __restrict__ hf)
{
    __shared__ float xl[F_NODE];
    int n = blockIdx.x, o = threadIdx.x;
    if (o < F_NODE) xl[o] = x[(size_t)n * F_NODE + o];
    __syncthreads();
    float acc = nb[o];
#pragma unroll 8
    for (int f = 0; f < F_NODE; ++f) acc += xl[f] * nw[f * HDIM + o];
    h [(size_t)n * HDIM + o] = acc;
    hf[(size_t)n * HDIM + o] = (_Float16)acc;
}

__global__ void k_deg(const int* __restrict__ dst, int* __restrict__ deg)
{
    int e = blockIdx.x * 256 + threadIdx.x;
    if (e < E_TOT) atomicAdd(&deg[dst[e]], 1);
}

__global__ void k_invd(const int* __restrict__ deg, float* __restrict__ invd)
{
    int n = blockIdx.x * 256 + threadIdx.x;
    if (n < N_NODES) invd[n] = deg[n] > 0 ? 1.0f / (float)deg[n] : 0.0f;
}

// ef = relu(edge_attr @ e1_w[l] + e1_b[l]) stored f16 [E][136] (16B rows;
// col128 = 1.0 bias chunk, cols 129..135 unused).
// 16 edges per block, 256 thr; w1 (8KB) staged in LDS once per block.
#define EF_STRIDE 136
__global__ __launch_bounds__(256)
void k_edge_mlp(const float* __restrict__ ea, const float* __restrict__ w1,
                const float* __restrict__ b1, _Float16* __restrict__ efg)
{
    __shared__ float al[16][17];
    __shared__ float wl[16][HDIM];
    __shared__ float bl[HDIM];
    int t = threadIdx.x, e0 = blockIdx.x * 16;
    if (t < HDIM) bl[t] = b1[t];
    for (int i = t; i < F_EDGE * HDIM; i += 256) wl[i >> 7][i & 127] = w1[i];
    { int i = t; al[i >> 4][i & 15] = ea[(size_t)e0 * F_EDGE + i]; }
    __syncthreads();
    int e = t >> 4, og = t & 15;
    float acc[8];
#pragma unroll
    for (int j = 0; j < 8; ++j) acc[j] = bl[og * 8 + j];
#pragma unroll
    for (int f = 0; f < F_EDGE; ++f) {
        float a = al[e][f];
#pragma unroll
        for (int j = 0; j < 8; ++j) acc[j] += a * wl[f][og * 8 + j];
    }
    half8 o;
#pragma unroll
    for (int j = 0; j < 8; ++j) o[j] = (_Float16)fmaxf(acc[j], 0.f);
    *(half8*)&efg[(size_t)(e0 + e) * EF_STRIDE + og * 8] = o;
    if (og == 0) efg[(size_t)(e0 + e) * EF_STRIDE + 128] = (_Float16)1.0f;
}

// ---------------------------------------------------------------------------
// msg[e,o] = sum_k ef[e,k] * (h[src[e],:] @ W2[k,:,:]) ; atomic scatter-add
// into agg (k-split partials merge via the atomics).
// FINAL (= round-11 champion, 65.4us/dispatch, session-best total 414.9us):
// barrier-free register streaming, BM=64, 4 waves col-split, KSPLIT=4 (one
// ks per XCD pair), HALF-granular B double-buffer (B0/B1) refilled right
// after last use.  16 falsification attempts established a ~1600 cyc/iter
// structural floor invariant to: MFMA shape (16x16x32 vs 32x32x16), waves/
// SIMD (2/3/4), RF (3/4/6), prefetch depth/placement, pinned vmcnt, LDS
// staging, block shape.  This configuration is the measured optimum.
// ---------------------------------------------------------------------------
#define BM 64
#define KSPLIT 4
__global__ __launch_bounds__(256, 3)
void k_msg(const _Float16* __restrict__ W2L,   // layer base: [129][32][512] f16
           const _Float16* __restrict__ efg,   // [E][136] f16
           const _Float16* __restrict__ hf,    // [N][128] f16
           const int* __restrict__ srcIdx,
           const int* __restrict__ dstIdx,
           float* __restrict__ agg,            // [N][128] f32
           float* __restrict__ bns1,
           float* __restrict__ bns2)
{
    __shared__ _Float16 efs[BM][40];    // local k-slice of ef (<=33 cols + pad)

    const int tid  = threadIdx.x;
    const int lane = tid & 63;
    const int w    = tid >> 6;          // wave 0..3, owns cols [w*32, w*32+32)
    const int lhi  = lane >> 4;         // 0..3
    const int llo  = lane & 15;

    // XCD-grouped decode: bx%8 -> XCD; XCD pair {2ks,2ks+1} serves slice ks.
    const int bx    = blockIdx.x;
    const int ks    = (bx & 7) >> 1;
    const int tile  = (bx >> 3) * 2 + (bx & 1);           // 0..191
    const int e0    = tile * BM;
    const int kbase = (129 * ks) >> 2;                    // 0,32,64,96
    const int kcnt  = ((129 * (ks + 1)) >> 2) - kbase;    // 32,32,32,33

    // zero BN partial sums for the k_out that follows (stream-ordered)
    if (bx == 0 && tid < HDIM) { bns1[tid] = 0.f; bns2[tid] = 0.f; }

    // stage ef k-slice (64 rows x 5 half8)
    for (int i = tid; i < BM * 5; i += 256) {
        int r = i / 5, c = i - r * 5;
        *(half8*)&efs[r][c * 8] =
            *(const half8*)(efg + (size_t)(e0 + r) * EF_STRIDE + kbase + c * 8);
    }

    // h_src fragments (all 64 rows; every wave needs all rows) in registers
    half8 hs[4][4];
#pragma unroll
    for (int rf = 0; rf < 4; ++rf) {
        int s = srcIdx[e0 + rf * 16 + llo];
        const _Float16* hp = hf + (size_t)s * HDIM + lhi * 8;
#pragma unroll
        for (int hc = 0; hc < 4; ++hc)
            hs[rf][hc] = *(const half8*)(hp + hc * 32);
    }

    __syncthreads();   // efs ready (only barrier in the kernel)

    // B fragment base: chunk = hc*8 + w*2 + cf ; offsets in f16 units:
    //   (kk)*16384 + hc*4096 + cf*512, lane offset lane*8 (16B/lane)
    const _Float16* bp = W2L + (size_t)kbase * 16384 + (w * 2) * 512 + lane * 8;

#define LDH(dst, kk, h2) do {                                          \
        const _Float16* p_ = bp + (size_t)(kk) * 16384 + (h2) * 8192;  \
        dst[0] = *(const half8*)(p_);                                  \
        dst[1] = *(const half8*)(p_ + 512);                            \
        dst[2] = *(const half8*)(p_ + 4096);                           \
        dst[3] = *(const half8*)(p_ + 4608);                           \
    } while (0)

    half8 B0[4], B1[4];
    LDH(B0, 0, 0);      // (k=0, hc 0-1) fragments
    LDH(B1, 0, 1);      // (k=0, hc 2-3) fragments

    f32x4 acc[4][2];
#pragma unroll
    for (int rf = 0; rf < 4; ++rf)
#pragma unroll
        for (int cf = 0; cf < 2; ++cf)
#pragma unroll
            for (int d = 0; d < 4; ++d) acc[rf][cf][d] = 0.f;

    for (int kk = 0; kk < kcnt; ++kk) {
        _Float16 efv[4];
#pragma unroll
        for (int rf = 0; rf < 4; ++rf) efv[rf] = efs[rf * 16 + llo][kk];

        // half 0: hc 0-1 from B0 (compiler inserts counted vmcnt before use)
#pragma unroll
        for (int rf = 0; rf < 4; ++rf) {
            half8 av0 = hs[rf][0] * efv[rf];
            half8 av1 = hs[rf][1] * efv[rf];
            acc[rf][0] = __builtin_amdgcn_mfma_f32_16x16x32_f16(av0, B0[0], acc[rf][0], 0, 0, 0);
            acc[rf][1] = __builtin_amdgcn_mfma_f32_16x16x32_f16(av0, B0[1], acc[rf][1], 0, 0, 0);
            acc[rf][0] = __builtin_amdgcn_mfma_f32_16x16x32_f16(av1, B0[2], acc[rf][0], 0, 0, 0);
            acc[rf][1] = __builtin_amdgcn_mfma_f32_16x16x32_f16(av1, B0[3], acc[rf][1], 0, 0, 0);
        }
        if (kk + 1 < kcnt) LDH(B0, kk + 1, 0);   // refill right after last use

        // half 1: hc 2-3 from B1
#pragma unroll
        for (int rf = 0; rf < 4; ++rf) {
            half8 av2 = hs[rf][2] * efv[rf];
            half8 av3 = hs[rf][3] * efv[rf];
            acc[rf][0] = __builtin_amdgcn_mfma_f32_16x16x32_f16(av2, B1[0], acc[rf][0], 0, 0, 0);
            acc[rf][1] = __builtin_amdgcn_mfma_f32_16x16x32_f16(av2, B1[1], acc[rf][1], 0, 0, 0);
            acc[rf][0] = __builtin_amdgcn_mfma_f32_16x16x32_f16(av3, B1[2], acc[rf][0], 0, 0, 0);
            acc[rf][1] = __builtin_amdgcn_mfma_f32_16x16x32_f16(av3, B1[3], acc[rf][1], 0, 0, 0);
        }
        if (kk + 1 < kcnt) LDH(B1, kk + 1, 1);
    }
#undef LDH

    // epilogue: scatter-add partial msg into agg[dst]
    // C/D layout: col=lane&15, row=(lane>>4)*4+reg
#pragma unroll
    for (int rf = 0; rf < 4; ++rf) {
#pragma unroll
        for (int r = 0; r < 4; ++r) {
            int row = rf * 16 + lhi * 4 + r;
            int d   = dstIdx[e0 + row];
#pragma unroll
            for (int cf = 0; cf < 2; ++cf) {
                int o = w * 32 + cf * 16 + llo;
                atomicAdd(&agg[(size_t)d * HDIM + o], acc[rf][cf][r]);
            }
        }
    }
}

// out = agg*inv_deg + h @ root_w[l] + conv_b[l]   (16 rows per block)
// 4x4 register tiles (128 thr); fused BN sum/sumsq via LDS reduce.
__global__ __launch_bounds__(128)
void k_out(const float* __restrict__ agg, const float* __restrict__ invd,
           const float* __restrict__ h, const float* __restrict__ rw,
           const float* __restrict__ cb, float* __restrict__ outb,
           float* __restrict__ bns1, float* __restrict__ bns2)
{
    __shared__ float hl[16][132];
    __shared__ float rb1[128], rb2[128];
    int t = threadIdx.x, n0 = blockIdx.x * 16;
    int rg = t >> 5, cg = t & 31;
    for (int i = t; i < 16 * HDIM; i += 128)
        hl[i >> 7][i & 127] = h[(size_t)(n0 + (i >> 7)) * HDIM + (i & 127)];
    rb1[t] = 0.f; rb2[t] = 0.f;
    __syncthreads();

    f32x4 cbv = *(const f32x4*)&cb[cg * 4];
    f32x4 acc[4];
#pragma unroll
    for (int i = 0; i < 4; ++i) {
        int r = n0 + rg * 4 + i;
        f32x4 a = *(const f32x4*)&agg[(size_t)r * HDIM + cg * 4];
        acc[i] = a * invd[r] + cbv;
    }
    for (int hh = 0; hh < HDIM; hh += 4) {
        f32x4 wv[4], hv[4];
#pragma unroll
        for (int j = 0; j < 4; ++j) wv[j] = *(const f32x4*)&rw[(hh + j) * HDIM + cg * 4];
#pragma unroll
        for (int i = 0; i < 4; ++i) hv[i] = *(const f32x4*)&hl[rg * 4 + i][hh];
#pragma unroll
        for (int i = 0; i < 4; ++i)
#pragma unroll
            for (int j = 0; j < 4; ++j)
                acc[i] += hv[i][j] * wv[j];
    }
    f32x4 s1v = {0.f,0.f,0.f,0.f}, s2v = {0.f,0.f,0.f,0.f};
#pragma unroll
    for (int i = 0; i < 4; ++i) {
        *(f32x4*)&outb[(size_t)(n0 + rg * 4 + i) * HDIM + cg * 4] = acc[i];
        s1v += acc[i];
        s2v += acc[i] * acc[i];
    }
#pragma unroll
    for (int j = 0; j < 4; ++j) {
        atomicAdd(&rb1[cg * 4 + j], s1v[j]);
        atomicAdd(&rb2[cg * 4 + j], s2v[j]);
    }
    __syncthreads();
    atomicAdd(&bns1[t], rb1[t]);
    atomicAdd(&bns2[t], rb2[t]);
}

// h += relu(bn(out)) with mu/rsig derived inline; refresh hf.
// Non-last layers: zero agg for the next layer's atomics.
// Last layer: fused global-mean-pool scatter.
__global__ void k_bn_apply(const float* __restrict__ outb, const float* __restrict__ bns1,
                           const float* __restrict__ bns2, const float* __restrict__ g,
                           const float* __restrict__ b, float* __restrict__ h,
                           _Float16* __restrict__ hf, float* __restrict__ agg,
                           const int* __restrict__ batch, float* __restrict__ pooled,
                           int* __restrict__ cnt, int last)
{
    int i = blockIdx.x * 256 + threadIdx.x;   // < N*128
    int o = i & (HDIM - 1);
    const float inv_n = 1.0f / (float)N_NODES;
    float m   = bns1[o] * inv_n;
    float var = bns2[o] * inv_n - m * m;
    float rs  = rsqrtf(var + 1e-5f);
    float v  = (outb[i] - m) * rs * g[o] + b[o];
    float hn = h[i] + fmaxf(v, 0.f);
    h[i]  = hn;
    hf[i] = (_Float16)hn;
    if (!last) {
        agg[i] = 0.f;
    } else {
        int n  = i >> 7;
        int gg = batch[n];
        atomicAdd(&pooled[(size_t)gg * HDIM + o], hn);
        if (o == 0) atomicAdd(&cnt[gg], 1);
    }
}

__global__ __launch_bounds__(128)
void k_head(const float* __restrict__ pooled, const int* __restrict__ cnt,
            const float* __restrict__ w1, const float* __restrict__ b1,
            const float* __restrict__ w2, const float* __restrict__ b2,
            float* __restrict__ y)
{
    __shared__ float pl[HDIM];
    __shared__ float red[HDIM];
    int g = blockIdx.x, o = threadIdx.x;
    float ic = 1.0f / (float)max(cnt[g], 1);
    pl[o] = pooled[(size_t)g * HDIM + o] * ic;
    __syncthreads();
    float t = b1[o];
#pragma unroll 8
    for (int hh = 0; hh < HDIM; ++hh) t += pl[hh] * w1[hh * HDIM + o];
    t = fmaxf(t, 0.f);
    red[o] = t * w2[o];
    __syncthreads();
    for (int s = 64; s > 0; s >>= 1) {
        if (o < s) red[o] += red[o + s];
        __syncthreads();
    }
    if (o == 0) y[g] = red[0] + b2[0];
}

// ---------------------------------------------------------------------------
extern "C" void kernel_launch(void* const* d_in, const int* in_sizes, int n_in,
                              void* d_out, int out_size, void* d_ws, size_t ws_size,
                              hipStream_t stream)
{
    const float* x      = (const float*)d_in[0];
    const int*   ei     = (const int*)  d_in[1];
    const float* ea     = (const float*)d_in[2];
    const int*   batch  = (const int*)  d_in[3];
    const float* node_w = (const float*)d_in[4];
    const float* node_b = (const float*)d_in[5];
    const float* e1w    = (const float*)d_in[6];
    const float* e1b    = (const float*)d_in[7];
    const float* e2w    = (const float*)d_in[8];
    const float* e2b    = (const float*)d_in[9];
    const float* rw     = (const float*)d_in[10];
    const float* cb     = (const float*)d_in[11];
    const float* bng    = (const float*)d_in[12];
    const float* bnb    = (const float*)d_in[13];
    const float* hw1    = (const float*)d_in[14];
    const float* hb1    = (const float*)d_in[15];
    const float* hw2    = (const float*)d_in[16];
    const float* hb2    = (const float*)d_in[17];
    float* y = (float*)d_out;

    // workspace carve-up (~27.8 MB, all 256B-aligned chunks)
    char* ws = (char*)d_ws;
    _Float16* W2F  = (_Float16*)ws; ws += 16908288;  // 4*129*16384 f16
    float*    h    = (float*)ws;    ws += 2097152;
    _Float16* hf   = (_Float16*)ws; ws += 1048576;
    _Float16* efg  = (_Float16*)ws; ws += 3342336;   // E*136 f16
    float*    agg  = (float*)ws;    ws += 2097152;   // [N][128] f32
    float*    bns1 = (float*)ws;    ws += 512;       // BN sum
    float*    bns2 = (float*)ws;    ws += 512;       // BN sumsq
    float*    outb = (float*)ws;    ws += 2097152;
    int*      deg  = (int*)ws;      ws += 16384;
    float*    invd = (float*)ws;    ws += 16384;
    float*    pooled = (float*)ws;  ws += 131072;
    int*      cnt  = (int*)ws;      ws += 1024;

    const int* src = ei;
    const int* dst = ei + E_TOT;

    k_prep_w2<<<NLAYER * 129, 256, 0, stream>>>(e2w, e2b, W2F);
    k_node_enc<<<N_NODES, 128, 0, stream>>>(x, node_w, node_b, h, hf);
    hipMemsetAsync(deg, 0, N_NODES * sizeof(int), stream);
    k_deg<<<(E_TOT + 255) / 256, 256, 0, stream>>>(dst, deg);
    k_invd<<<(N_NODES + 255) / 256, 256, 0, stream>>>(deg, invd);
    // agg zero for layer 0; pooled+cnt zero (contiguous => one memset)
    hipMemsetAsync(agg, 0, (size_t)N_NODES * HDIM * sizeof(float), stream);
    hipMemsetAsync(pooled, 0, (size_t)NGRAPH * HDIM * sizeof(float) + NGRAPH * sizeof(int), stream);

    for (int l = 0; l < NLAYER; ++l) {
        k_edge_mlp<<<E_TOT / 16, 256, 0, stream>>>(ea, e1w + l * F_EDGE * HDIM,
                                                   e1b + l * HDIM, efg);
        k_msg<<<(E_TOT / BM) * KSPLIT, 256, 0, stream>>>(
            W2F + (size_t)l * 129 * 16384, efg, hf, src, dst, agg, bns1, bns2);
        k_out<<<N_NODES / 16, 128, 0, stream>>>(agg, invd, h,
                                                rw + l * HDIM * HDIM,
                                                cb + l * HDIM, outb, bns1, bns2);
        k_bn_apply<<<(N_NODES * HDIM) / 256, 256, 0, stream>>>(
            outb, bns1, bns2, bng + l * HDIM, bnb + l * HDIM, h, hf,
            agg, batch, pooled, cnt, (l == NLAYER - 1) ? 1 : 0);
    }

    k_head<<<NGRAPH, 128, 0, stream>>>(pooled, cnt, hw1, hb1, hw2, hb2, y);
}